// Round 18
// baseline (625.401 us; speedup 1.0000x reference)
//
#include <hip/hip_runtime.h>

#define B_ 64
#define T_ 256
#define D_ 300
#define DP_ 320
#define H_ 256
#define G_ 1024
#define N_ 8

typedef unsigned int u32;
typedef unsigned short u16;
typedef __attribute__((ext_vector_type(8))) short short8;
typedef __attribute__((ext_vector_type(4))) float f32x4;
typedef __attribute__((ext_vector_type(4))) u32 u32x4;
typedef __attribute__((ext_vector_type(2))) u32 u32x2;
typedef _Float16 h2 __attribute__((ext_vector_type(2)));
typedef __fp16 fp16x2 __attribute__((ext_vector_type(2)));

__device__ __forceinline__ u16 f2bf(float f){
  union {float f; u32 u;} v; v.f = f;
  u32 r = (v.u + 0x7fffu + ((v.u>>16)&1u)) >> 16;
  return (u16)r;
}
__device__ __forceinline__ float bflo(u32 u){
  union {u32 u; float f;} v; v.u = u<<16; return v.f;
}
__device__ __forceinline__ float bfhi(u32 u){
  union {u32 u; float f;} v; v.u = u & 0xffff0000u; return v.f;
}
__device__ __forceinline__ float rcp_(float x){
#if __has_builtin(__builtin_amdgcn_rcpf)
  return __builtin_amdgcn_rcpf(x);
#else
  return 1.0f/x;
#endif
}
__device__ __forceinline__ float sigm(float x){ return rcp_(1.0f + __expf(-x)); }
__device__ __forceinline__ float tanh_(float x){ return fmaf(2.0f, rcp_(1.0f + __expf(-2.0f*x)), -1.0f); }

__device__ __forceinline__ float fdot2(u32 a, u32 b, float c){
  union { u32 u; h2 h; } ua, ub; ua.u = a; ub.u = b;
#if __has_builtin(__builtin_amdgcn_fdot2)
  return __builtin_amdgcn_fdot2(ua.h, ub.h, c, false);
#else
  return c + (float)ua.h.x*(float)ub.h.x + (float)ua.h.y*(float)ub.h.y;
#endif
}
__device__ __forceinline__ u32 pkf16(float a, float b){
  union { fp16x2 h; u32 u; } v; v.h = __builtin_amdgcn_cvt_pkrtz(a, b); return v.u;
}
// 8-lane butterfly sum via DPP (VALU pipe): 3 stages — xor1, xor2, then
// row_half_mirror (l -> 7-l == l^7 within each 8-lane half-row; valid as a
// cross-quad fetch because the value is quad-uniform after stages 1-2).
__device__ __forceinline__ float qred8(float v){
  union {float f; int i;} u, t;
  u.f = v;
  t.i = __builtin_amdgcn_mov_dpp(u.i, 0xB1, 0xF, 0xF, true);   // quad_perm(1,0,3,2)
  u.f += t.f;
  t.i = __builtin_amdgcn_mov_dpp(u.i, 0x4E, 0xF, 0xF, true);   // quad_perm(2,3,0,1)
  u.f += t.f;
  t.i = __builtin_amdgcn_mov_dpp(u.i, 0x141, 0xF, 0xF, true);  // row_half_mirror
  return u.f + t.f;
}

// ---------------- K1: mixture coefficients c[b][8] ----------------
__global__ void __launch_bounds__(64) k_coef(
    const int* __restrict__ uidx, const int* __restrict__ iidx,
    const float* __restrict__ uemb, const float* __restrict__ iemb,
    const float* __restrict__ W1, const float* __restrict__ b1,
    const float* __restrict__ W2, float* __restrict__ coef)
{
  __shared__ float q[128];
  __shared__ float hid[64];
  __shared__ float lg[8];
  int b = blockIdx.x, t = threadIdx.x;
  int u = uidx[b], it = iidx[b];
  q[t]      = uemb[(size_t)u*64 + t];
  q[64 + t] = iemb[(size_t)it*64 + t];
  __syncthreads();
  float s = b1[t];
  for (int j = 0; j < 128; ++j) s = fmaf(q[j], W1[j*64 + t], s);
  hid[t] = tanhf(s);
  __syncthreads();
  if (t < 8) {
    float s2 = 0.f;
    for (int j = 0; j < 64; ++j) s2 = fmaf(hid[j], W2[j*8 + t], s2);
    lg[t] = s2;
  }
  __syncthreads();
  if (t == 0) {
    float mx = lg[0];
    for (int n = 1; n < 8; ++n) mx = fmaxf(mx, lg[n]);
    float e[8], den = 0.f;
    for (int n = 0; n < 8; ++n){ e[n] = __expf(lg[n]-mx); den += e[n]; }
    for (int n = 0; n < 8; ++n) coef[b*8+n] = e[n]/den;
  }
}

// ---------------- K2a: mix Whh (+bias) into packed f16 blob ----------------
// NEW k_rec decomposition: thread tid2 = gset*8 + r (gset in [0,128): owns the
// 8 gates {gset*8+l}; r in [0,8): owns col pairs [r*16, r*16+16)).
// Slot quads j in [0,32): j = pe*2 + gh; pe = cidx*4 + e selects the pair
// p = r*16 + ((cidx+r)&3)*4 + e (rotation baked in for bank-spread h reads);
// gh selects gate half (gates gset*8 + gh*4 .. +gh*4+3 across the 4 lanes).
// blob layout: [chain][j (32)][tid2 (1024)][lane (4)] u32 = 64 MB.
// blockIdx.x == gset (covers tid2 [gblk*8, gblk*8+8)); staging unchanged.
// blockIdx.z in {0,1}: batches [z*32, z*32+32).
__global__ void __launch_bounds__(256) k_mix_whh(
    const float* __restrict__ Whh_f, const float* __restrict__ Whh_r,
    const float* __restrict__ bias_f, const float* __restrict__ bias_r,
    const float* __restrict__ coef, u32* __restrict__ blob, float* __restrict__ bias_m)
{
  int gblk = blockIdx.x;   // = gset
  int dir  = blockIdx.y;
  int b0   = blockIdx.z * 32;
  int tid  = threadIdx.x;  // = ii*8 + t2l
  const float* Wsel = dir ? Whh_r : Whh_f;
  const float* bsel = dir ? bias_r : bias_f;
  __shared__ float bs[N_][8][H_];   // 64 KB: gates gblk*8..gblk*8+8
  for (int v = 0; v < 64; ++v){
    int i = v*256 + tid;
    int n = i >> 11, gl = (i >> 8) & 7, c = i & 255;
    bs[n][gl][c] = Wsel[((size_t)n*G_ + gblk*8 + gl)*H_ + c];
  }
  __syncthreads();
  int t2l = tid & 7, ii = tid >> 3;   // t2l = r, ii = slot quad j in [0,32)
  int tid2 = gblk*8 + t2l;
  int r = t2l;
  int pe = ii >> 1, gh = ii & 1;
  int cx = pe >> 2, e = pe & 3;
  int p = r*16 + ((cx + r)&3)*4 + e;          // this quad's column-pair
  float bw0[4][8], bw1[4][8];
  #pragma unroll
  for (int l4 = 0; l4 < 4; ++l4){
    int gl = gh*4 + l4;
    #pragma unroll
    for (int n = 0; n < 8; ++n){
      bw0[l4][n] = bs[n][gl][2*p];
      bw1[l4][n] = bs[n][gl][2*p + 1];
    }
  }
  for (int bb_ = 0; bb_ < 32; ++bb_){
    int b = b0 + bb_;
    float c8[8];
    #pragma unroll
    for (int n = 0; n < 8; ++n) c8[n] = coef[b*8+n];
    u32x4 ov;
    #pragma unroll
    for (int l4 = 0; l4 < 4; ++l4){
      float w0 = 0.f, w1 = 0.f;
      #pragma unroll
      for (int n = 0; n < 8; ++n){ w0 = fmaf(c8[n], bw0[l4][n], w0); w1 = fmaf(c8[n], bw1[l4][n], w1); }
      ov[l4] = pkf16(w0, w1);
    }
    size_t chain = (size_t)(dir*B_ + b);
    *(u32x4*)(blob + ((chain*32 + ii)*1024 + tid2)*4) = ov;
    if (tid < 8){
      float bv = 0.f;
      #pragma unroll
      for (int n = 0; n < 8; ++n) bv = fmaf(c8[n], bsel[n*G_ + gblk*8 + tid], bv);
      bias_m[chain*G_ + gblk*8 + tid] = bv;
    }
  }
}

// ---------------- K2b: mix Wih into bf16 [dir][b][g][320] (zero-padded) ----------------
// blockIdx.z in {0,1}: batches [z*32, z*32+32).
__global__ void __launch_bounds__(256) k_mix_wi(
    const float* __restrict__ Wih_f, const float* __restrict__ Wih_r,
    const float* __restrict__ coef, u32* __restrict__ WimU)
{
  int gblk = blockIdx.x;
  int dir  = blockIdx.y;
  int b0   = blockIdx.z * 32;
  int tid  = threadIdx.x;
  const float* Wsel = dir ? Wih_r : Wih_f;
  __shared__ float bs[N_][8][D_];   // 76.8 KB
  for (int v = 0; v < 75; ++v){
    int i = v*256 + tid;            // < 19200
    int n = i/2400, rem = i%2400, gl = rem/300, c = rem%300;
    bs[n][gl][c] = Wsel[((size_t)n*G_ + gblk*8 + gl)*D_ + c];
  }
  __syncthreads();
  float bw[5][2][8];
  int rowv[5], cpv[5];
  #pragma unroll
  for (int v = 0; v < 5; ++v){
    int idx = v*256 + tid;          // < 1280
    int row = idx/160, cp = idx%160;
    rowv[v] = row; cpv[v] = cp;
    #pragma unroll
    for (int n = 0; n < 8; ++n){
      bw[v][0][n] = (cp < 150) ? bs[n][row][2*cp]   : 0.f;
      bw[v][1][n] = (cp < 150) ? bs[n][row][2*cp+1] : 0.f;
    }
  }
  for (int bb_ = 0; bb_ < 32; ++bb_){
    int b = b0 + bb_;
    float c8[8];
    #pragma unroll
    for (int n = 0; n < 8; ++n) c8[n] = coef[b*8+n];
    #pragma unroll
    for (int v = 0; v < 5; ++v){
      float w0 = 0.f, w1 = 0.f;
      #pragma unroll
      for (int n = 0; n < 8; ++n){ w0 = fmaf(c8[n], bw[v][0][n], w0); w1 = fmaf(c8[n], bw[v][1][n], w1); }
      WimU[(((size_t)(dir*B_+b)*G_ + gblk*8 + rowv[v])*160) + cpv[v]] = (u32)f2bf(w0) | ((u32)f2bf(w1) << 16);
    }
  }
}

// ---------------- K2c: x -> bf16, padded to 320 ----------------
__global__ void __launch_bounds__(256) k_xpad(const float* __restrict__ x, u32* __restrict__ xpadU)
{
  int o = blockIdx.x*256 + threadIdx.x;   // < 64*256*160
  int bt = o/160, cp = o%160;
  float v0 = (cp < 150) ? x[(size_t)bt*D_ + 2*cp]   : 0.f;
  float v1 = (cp < 150) ? x[(size_t)bt*D_ + 2*cp+1] : 0.f;
  xpadU[o] = (u32)f2bf(v0) | ((u32)f2bf(v1) << 16);
}

// ---------------- K3: xproj[dir][b][t][g] (bf16) = xpad[b] @ Wim[dir][b]^T + bias ----------------
// Proven round-10 config: __launch_bounds__(256,2). (256,4) regressed (round 16).
__global__ void __launch_bounds__(256,2) k_gemm(
    const u16* __restrict__ xpad, const u16* __restrict__ Wim,
    const float* __restrict__ bias_m, u16* __restrict__ xproj)
{
  int bx = blockIdx.x;
  int b  = blockIdx.y, dir = blockIdx.z;
  int tt = bx >> 3, tg = bx & 7;
  int tid = threadIdx.x;
  int wid = tid >> 6, lane = tid & 63;
  int wr = wid >> 1, wc = wid & 1;
  __shared__ u16 As[128][72];
  __shared__ u16 Bs[128][72];
  const u16* Ap = xpad + ((size_t)b*T_ + tt*128)*DP_;
  const u16* Bp = Wim + (((size_t)dir*B_ + b)*G_ + tg*128)*DP_;
  f32x4 acc[4][4];
  #pragma unroll
  for (int i = 0; i < 4; ++i)
    #pragma unroll
    for (int j = 0; j < 4; ++j) acc[i][j] = (f32x4){0.f,0.f,0.f,0.f};
  for (int kt = 0; kt < 5; ++kt){
    int k0 = kt*64;
    #pragma unroll
    for (int i = 0; i < 4; ++i){
      int ci = i*256 + tid;
      int row = ci >> 3, cc = (ci & 7)*8;
      *(u32x4*)&As[row][cc] = *(const u32x4*)(Ap + (size_t)row*DP_ + k0 + cc);
      *(u32x4*)&Bs[row][cc] = *(const u32x4*)(Bp + (size_t)row*DP_ + k0 + cc);
    }
    __syncthreads();
    #pragma unroll
    for (int kk = 0; kk < 2; ++kk){
      short8 af[4], bfr[4];
      #pragma unroll
      for (int mi = 0; mi < 4; ++mi) af[mi]  = *(const short8*)&As[wr*64 + mi*16 + (lane&15)][kk*32 + (lane>>4)*8];
      #pragma unroll
      for (int ni = 0; ni < 4; ++ni) bfr[ni] = *(const short8*)&Bs[wc*64 + ni*16 + (lane&15)][kk*32 + (lane>>4)*8];
      #pragma unroll
      for (int mi = 0; mi < 4; ++mi)
        #pragma unroll
        for (int ni = 0; ni < 4; ++ni)
          acc[mi][ni] = __builtin_amdgcn_mfma_f32_16x16x32_bf16(af[mi], bfr[ni], acc[mi][ni], 0,0,0);
    }
    __syncthreads();
  }
  int r4 = (lane >> 4)*4, cg = lane & 15;
  const float* bmp = bias_m + (size_t)(dir*B_ + b)*G_;
  #pragma unroll
  for (int ni = 0; ni < 4; ++ni){
    int g = tg*128 + wc*64 + ni*16 + cg;
    float bsv = bmp[g];
    #pragma unroll
    for (int mi = 0; mi < 4; ++mi)
      #pragma unroll
      for (int j = 0; j < 4; ++j){
        int t = tt*128 + wr*64 + mi*16 + r4 + j;
        xproj[(((size_t)dir*B_ + b)*T_ + t)*G_ + g] = f2bf(acc[mi][ni][j] + bsv);
      }
  }
}

// ---------------- K4: recurrence, one chain (b,dir) per workgroup ----------------
// Round-10 two-phase structure (proven) with NEW thread remap: tid = gset*8 + r.
// gset owns 8 gates {gset*8+l}; r owns col pairs [r*16, r*16+16).
// Halves the h-broadcast LDS traffic (4 b128/thread/step instead of 8);
// weight residency unchanged (96 words VGPR/AGPR + 32 LDS).
// 3-stage DPP butterfly (qred8); gates8 tail phase (wave-uniform tid<256);
// two __syncthreads; fast rcp/exp activations.
__global__ void __launch_bounds__(1024) k_rec(
    const u32* __restrict__ blob, const u32* __restrict__ xprojU,
    const int* __restrict__ length, float* __restrict__ out)
{
  int chain = blockIdx.x;
  int dir = chain >> 6, b = chain & 63;
  int tid = threadIdx.x;
  int gset = tid >> 3, r = tid & 7;
  __shared__ u32 wlds[8][1024][4];            // 128 KB: slot-quads 24..31
  __shared__ __align__(16) float gates8[1024]; // 4 KB: gates8[g] = gate g
  __shared__ __align__(16) u16 hp16[256];     // 512 B: h as f16
  const u32* hp32 = (const u32*)hp16;

  u32 w[96];
  const u32* bp = blob + (size_t)chain*32*1024*4;
  #pragma unroll
  for (int ii = 0; ii < 24; ++ii){
    u32x4 v = *(const u32x4*)(bp + ((size_t)ii*1024 + tid)*4);
    w[4*ii] = v.x; w[4*ii+1] = v.y; w[4*ii+2] = v.z; w[4*ii+3] = v.w;
  }
  #pragma unroll
  for (int ii = 24; ii < 32; ++ii){
    u32x4 v = *(const u32x4*)(bp + ((size_t)ii*1024 + tid)*4);
    *(u32x4*)&wlds[ii-24][tid][0] = v;
  }
  if (tid < 256) hp16[tid] = 0;
  int len = length[b];
  const u32* xp = xprojU + (size_t)chain*T_*512;
  float* outp = out + (size_t)b*T_*512 + dir*H_;
  float cst = 0.f;
  __syncthreads();

  for (int step = 0; step < len; ++step){
    int t = dir ? (len-1-step) : step;
    u32x4 xv = (u32x4){0,0,0,0};
    if (r == 0)
      xv = *(const u32x4*)(xp + (size_t)t*512 + gset*4);   // gates gset*8..+7 (bf16)
    float a0=0.f,a1=0.f,a2=0.f,a3=0.f,a4=0.f,a5=0.f,a6=0.f,a7=0.f;
    #pragma unroll
    for (int cx = 0; cx < 4; ++cx){
      int c4 = (cx + r) & 3;
      u32x4 hq = *(const u32x4*)&hp32[r*16 + c4*4];
      if (cx < 3){
        #pragma unroll
        for (int e = 0; e < 4; ++e){
          int pe = cx*4 + e;
          u32 hv = hq[e];
          a0 = fdot2(w[(pe*2+0)*4 + 0], hv, a0);
          a1 = fdot2(w[(pe*2+0)*4 + 1], hv, a1);
          a2 = fdot2(w[(pe*2+0)*4 + 2], hv, a2);
          a3 = fdot2(w[(pe*2+0)*4 + 3], hv, a3);
          a4 = fdot2(w[(pe*2+1)*4 + 0], hv, a4);
          a5 = fdot2(w[(pe*2+1)*4 + 1], hv, a5);
          a6 = fdot2(w[(pe*2+1)*4 + 2], hv, a6);
          a7 = fdot2(w[(pe*2+1)*4 + 3], hv, a7);
        }
      } else {
        #pragma unroll
        for (int e = 0; e < 4; ++e){
          int pe = cx*4 + e;          // 12..15 -> slot quads 24..31
          u32 hv = hq[e];
          u32x4 wv0 = *(const u32x4*)&wlds[pe*2+0-24][tid][0];
          u32x4 wv1 = *(const u32x4*)&wlds[pe*2+1-24][tid][0];
          a0 = fdot2(wv0.x, hv, a0);
          a1 = fdot2(wv0.y, hv, a1);
          a2 = fdot2(wv0.z, hv, a2);
          a3 = fdot2(wv0.w, hv, a3);
          a4 = fdot2(wv1.x, hv, a4);
          a5 = fdot2(wv1.y, hv, a5);
          a6 = fdot2(wv1.z, hv, a6);
          a7 = fdot2(wv1.w, hv, a7);
        }
      }
    }
    // 8-lane butterfly on VALU (DPP): all lanes of the r-group get full sums
    a0 = qred8(a0); a1 = qred8(a1); a2 = qred8(a2); a3 = qred8(a3);
    a4 = qred8(a4); a5 = qred8(a5); a6 = qred8(a6); a7 = qred8(a7);
    if (r == 0){
      a0 += bflo(xv.x); a1 += bfhi(xv.x); a2 += bflo(xv.y); a3 += bfhi(xv.y);
      a4 += bflo(xv.z); a5 += bfhi(xv.z); a6 += bflo(xv.w); a7 += bfhi(xv.w);
      f32x4 g4a; g4a.x=a0; g4a.y=a1; g4a.z=a2; g4a.w=a3;
      f32x4 g4b; g4b.x=a4; g4b.y=a5; g4b.z=a6; g4b.w=a7;
      *(f32x4*)&gates8[gset*8 + 0] = g4a;
      *(f32x4*)&gates8[gset*8 + 4] = g4b;
    }
    __syncthreads();
    if (tid < 256){
      const float* gf = &gates8[0];   // gf[g] = gate g
      float ig = gf[tid],       fg = gf[256 + tid];
      float g_ = gf[512 + tid], og = gf[768 + tid];
      float i_ = sigm(ig), f_ = sigm(fg), gt = tanh_(g_), o_ = sigm(og);
      float cn = fmaf(f_, cst, i_*gt);
      float hy = o_ * tanh_(cn);
      cst = cn;
      ((u16*)hp16)[tid] = (u16)(pkf16(hy, hy) & 0xffffu);
      outp[(size_t)t*512 + tid] = hy;
    }
    __syncthreads();
  }
}

extern "C" void kernel_launch(void* const* d_in, const int* in_sizes, int n_in,
                              void* d_out, int out_size, void* d_ws, size_t ws_size,
                              hipStream_t stream)
{
  const float* x      = (const float*)d_in[0];
  const int*   length = (const int*)d_in[1];
  const int*   uidx   = (const int*)d_in[2];
  const int*   iidx   = (const int*)d_in[3];
  const float* uemb   = (const float*)d_in[4];
  const float* iemb   = (const float*)d_in[5];
  const float* W1     = (const float*)d_in[6];
  const float* b1     = (const float*)d_in[7];
  const float* W2     = (const float*)d_in[8];
  const float* Wih    = (const float*)d_in[9];
  const float* Whh    = (const float*)d_in[10];
  const float* bias   = (const float*)d_in[11];
  const float* Wih_r  = (const float*)d_in[12];
  const float* Whh_r  = (const float*)d_in[13];
  const float* bias_r = (const float*)d_in[14];
  float* out = (float*)d_out;
  char* ws = (char*)d_ws;

  float* coef   = (float*)(ws + 0);              //      2,048
  float* bias_m = (float*)(ws + 2048);           //    524,288
  u32*   blob   = (u32*)  (ws + 526336);         // 67,108,864 region (64 MB used)
  u16*   Wim    = (u16*)  (ws + 67635200);       // 83,886,080
  u16*   xpad   = (u16*)  (ws + 151521280);      // 10,485,760
  u16*   xproj  = (u16*)  (ws + 162007040);      // 67,108,864  -> total 229,115,904

  (void)hipMemsetAsync(d_out, 0, (size_t)out_size*sizeof(float), stream);
  if (ws_size < 229115904ull) return;  // fail loudly (all-zero output) if workspace too small

  hipLaunchKernelGGL(k_coef,    dim3(64),       dim3(64),   0, stream, uidx, iidx, uemb, iemb, W1, b1, W2, coef);
  hipLaunchKernelGGL(k_mix_whh, dim3(128,2,2),  dim3(256),  0, stream, Whh, Whh_r, bias, bias_r, coef, blob, bias_m);
  hipLaunchKernelGGL(k_mix_wi,  dim3(128,2,2),  dim3(256),  0, stream, Wih, Wih_r, coef, (u32*)Wim);
  hipLaunchKernelGGL(k_xpad,    dim3(10240),    dim3(256),  0, stream, x, (u32*)xpad);
  hipLaunchKernelGGL(k_gemm,    dim3(16,64,2),  dim3(256),  0, stream, xpad, Wim, bias_m, xproj);
  hipLaunchKernelGGL(k_rec,     dim3(128),      dim3(1024), 0, stream, blob, (const u32*)xproj, length, out);
}

// Round 19
// 571.414 us; speedup vs baseline: 1.0945x; 1.0945x over previous
//
#include <hip/hip_runtime.h>

#define B_ 64
#define T_ 256
#define D_ 300
#define DP_ 320
#define H_ 256
#define G_ 1024
#define N_ 8

typedef unsigned int u32;
typedef unsigned short u16;
typedef __attribute__((ext_vector_type(8))) short short8;
typedef __attribute__((ext_vector_type(4))) float f32x4;
typedef __attribute__((ext_vector_type(4))) u32 u32x4;
typedef __attribute__((ext_vector_type(2))) u32 u32x2;
typedef _Float16 h2 __attribute__((ext_vector_type(2)));
typedef __fp16 fp16x2 __attribute__((ext_vector_type(2)));

__device__ __forceinline__ u16 f2bf(float f){
  union {float f; u32 u;} v; v.f = f;
  u32 r = (v.u + 0x7fffu + ((v.u>>16)&1u)) >> 16;
  return (u16)r;
}
__device__ __forceinline__ float bflo(u32 u){
  union {u32 u; float f;} v; v.u = u<<16; return v.f;
}
__device__ __forceinline__ float bfhi(u32 u){
  union {u32 u; float f;} v; v.u = u & 0xffff0000u; return v.f;
}
__device__ __forceinline__ float rcp_(float x){
#if __has_builtin(__builtin_amdgcn_rcpf)
  return __builtin_amdgcn_rcpf(x);
#else
  return 1.0f/x;
#endif
}
__device__ __forceinline__ float sigm(float x){ return rcp_(1.0f + __expf(-x)); }
__device__ __forceinline__ float tanh_(float x){ return fmaf(2.0f, rcp_(1.0f + __expf(-2.0f*x)), -1.0f); }

__device__ __forceinline__ float fdot2(u32 a, u32 b, float c){
  union { u32 u; h2 h; } ua, ub; ua.u = a; ub.u = b;
#if __has_builtin(__builtin_amdgcn_fdot2)
  return __builtin_amdgcn_fdot2(ua.h, ub.h, c, false);
#else
  return c + (float)ua.h.x*(float)ub.h.x + (float)ua.h.y*(float)ub.h.y;
#endif
}
__device__ __forceinline__ u32 pkf16(float a, float b){
  union { fp16x2 h; u32 u; } v; v.h = __builtin_amdgcn_cvt_pkrtz(a, b); return v.u;
}
// quad butterfly sum via DPP (VALU pipe, NOT the LDS pipe like __shfl_xor):
// lanes 4k..4k+3 all end with the quad sum
__device__ __forceinline__ float qred(float v){
  union {float f; int i;} u, t;
  u.f = v;
  t.i = __builtin_amdgcn_mov_dpp(u.i, 0xB1, 0xF, 0xF, true);  // quad_perm(1,0,3,2)
  u.f += t.f;
  t.i = __builtin_amdgcn_mov_dpp(u.i, 0x4E, 0xF, 0xF, true);  // quad_perm(2,3,0,1)
  return u.f + t.f;
}

// ---------------- K1: mixture coefficients c[b][8] ----------------
__global__ void __launch_bounds__(64) k_coef(
    const int* __restrict__ uidx, const int* __restrict__ iidx,
    const float* __restrict__ uemb, const float* __restrict__ iemb,
    const float* __restrict__ W1, const float* __restrict__ b1,
    const float* __restrict__ W2, float* __restrict__ coef)
{
  __shared__ float q[128];
  __shared__ float hid[64];
  __shared__ float lg[8];
  int b = blockIdx.x, t = threadIdx.x;
  int u = uidx[b], it = iidx[b];
  q[t]      = uemb[(size_t)u*64 + t];
  q[64 + t] = iemb[(size_t)it*64 + t];
  __syncthreads();
  float s = b1[t];
  for (int j = 0; j < 128; ++j) s = fmaf(q[j], W1[j*64 + t], s);
  hid[t] = tanhf(s);
  __syncthreads();
  if (t < 8) {
    float s2 = 0.f;
    for (int j = 0; j < 64; ++j) s2 = fmaf(hid[j], W2[j*8 + t], s2);
    lg[t] = s2;
  }
  __syncthreads();
  if (t == 0) {
    float mx = lg[0];
    for (int n = 1; n < 8; ++n) mx = fmaxf(mx, lg[n]);
    float e[8], den = 0.f;
    for (int n = 0; n < 8; ++n){ e[n] = __expf(lg[n]-mx); den += e[n]; }
    for (int n = 0; n < 8; ++n) coef[b*8+n] = e[n]/den;
  }
}

// ---------------- K2a: mix Whh (+bias) into packed f16 blob ----------------
// k_rec decomposition: thread tid2 = gg*4 + q (gg in [0,256): gates 4gg..4gg+3;
// q in [0,4): col pairs p in [32q, 32q+32)). Per-thread slots i in [0,128):
//   i = cidx*16 + e*4 + l  -> gate 4gg+l, pair p = q*32 + ((cidx+2q)&7)*4 + e.
// blob layout: [chain][i>>2 (32)][tid2 (1024)][i&3] u32 = 64 MB.
// blockIdx.z in {0,1}: batches [z*32, z*32+32) — 2 blocks/CU, halved serial b-loop.
__global__ void __launch_bounds__(256) k_mix_whh(
    const float* __restrict__ Whh_f, const float* __restrict__ Whh_r,
    const float* __restrict__ bias_f, const float* __restrict__ bias_r,
    const float* __restrict__ coef, u32* __restrict__ blob, float* __restrict__ bias_m)
{
  int gblk = blockIdx.x;   // 0..127: gates [gblk*8, gblk*8+8) == tid2 [gblk*8, gblk*8+8)
  int dir  = blockIdx.y;
  int b0   = blockIdx.z * 32;
  int tid  = threadIdx.x;  // = ii*8 + t2l
  const float* Wsel = dir ? Whh_r : Whh_f;
  const float* bsel = dir ? bias_r : bias_f;
  __shared__ float bs[N_][8][H_];   // 64 KB
  for (int v = 0; v < 64; ++v){
    int i = v*256 + tid;
    int n = i >> 11, gl = (i >> 8) & 7, c = i & 255;
    bs[n][gl][c] = Wsel[((size_t)n*G_ + gblk*8 + gl)*H_ + c];
  }
  __syncthreads();
  int t2l = tid & 7, ii = tid >> 3;   // t2l in [0,8), ii in [0,32)
  int tid2 = gblk*8 + t2l;
  int gg = tid2 >> 2, q = tid2 & 3;
  int cidx = ii >> 2, e = ii & 3;
  int p = q*32 + ((cidx + 2*q)&7)*4 + e;     // this thread's column-pair
  int glbase = gg*4 - gblk*8;                 // 0 or 4
  float bw0[4][8], bw1[4][8];
  #pragma unroll
  for (int l = 0; l < 4; ++l)
    #pragma unroll
    for (int n = 0; n < 8; ++n){
      bw0[l][n] = bs[n][glbase + l][2*p];
      bw1[l][n] = bs[n][glbase + l][2*p + 1];
    }
  for (int bb_ = 0; bb_ < 32; ++bb_){
    int b = b0 + bb_;
    float c8[8];
    #pragma unroll
    for (int n = 0; n < 8; ++n) c8[n] = coef[b*8+n];
    u32x4 ov;
    #pragma unroll
    for (int l = 0; l < 4; ++l){
      float w0 = 0.f, w1 = 0.f;
      #pragma unroll
      for (int n = 0; n < 8; ++n){ w0 = fmaf(c8[n], bw0[l][n], w0); w1 = fmaf(c8[n], bw1[l][n], w1); }
      ov[l] = pkf16(w0, w1);
    }
    size_t chain = (size_t)(dir*B_ + b);
    *(u32x4*)(blob + ((chain*32 + ii)*1024 + tid2)*4) = ov;
    if (tid < 8){
      float bv = 0.f;
      #pragma unroll
      for (int n = 0; n < 8; ++n) bv = fmaf(c8[n], bsel[n*G_ + gblk*8 + tid], bv);
      bias_m[chain*G_ + gblk*8 + tid] = bv;
    }
  }
}

// ---------------- K2b: mix Wih into bf16 [dir][b][g][320] (zero-padded) ----------------
// blockIdx.z in {0,1}: batches [z*32, z*32+32).
__global__ void __launch_bounds__(256) k_mix_wi(
    const float* __restrict__ Wih_f, const float* __restrict__ Wih_r,
    const float* __restrict__ coef, u32* __restrict__ WimU)
{
  int gblk = blockIdx.x;
  int dir  = blockIdx.y;
  int b0   = blockIdx.z * 32;
  int tid  = threadIdx.x;
  const float* Wsel = dir ? Wih_r : Wih_f;
  __shared__ float bs[N_][8][D_];   // 76.8 KB
  for (int v = 0; v < 75; ++v){
    int i = v*256 + tid;            // < 19200
    int n = i/2400, rem = i%2400, gl = rem/300, c = rem%300;
    bs[n][gl][c] = Wsel[((size_t)n*G_ + gblk*8 + gl)*D_ + c];
  }
  __syncthreads();
  float bw[5][2][8];
  int rowv[5], cpv[5];
  #pragma unroll
  for (int v = 0; v < 5; ++v){
    int idx = v*256 + tid;          // < 1280
    int row = idx/160, cp = idx%160;
    rowv[v] = row; cpv[v] = cp;
    #pragma unroll
    for (int n = 0; n < 8; ++n){
      bw[v][0][n] = (cp < 150) ? bs[n][row][2*cp]   : 0.f;
      bw[v][1][n] = (cp < 150) ? bs[n][row][2*cp+1] : 0.f;
    }
  }
  for (int bb_ = 0; bb_ < 32; ++bb_){
    int b = b0 + bb_;
    float c8[8];
    #pragma unroll
    for (int n = 0; n < 8; ++n) c8[n] = coef[b*8+n];
    #pragma unroll
    for (int v = 0; v < 5; ++v){
      float w0 = 0.f, w1 = 0.f;
      #pragma unroll
      for (int n = 0; n < 8; ++n){ w0 = fmaf(c8[n], bw[v][0][n], w0); w1 = fmaf(c8[n], bw[v][1][n], w1); }
      WimU[(((size_t)(dir*B_+b)*G_ + gblk*8 + rowv[v])*160) + cpv[v]] = (u32)f2bf(w0) | ((u32)f2bf(w1) << 16);
    }
  }
}

// ---------------- K2c: x -> bf16, padded to 320 ----------------
__global__ void __launch_bounds__(256) k_xpad(const float* __restrict__ x, u32* __restrict__ xpadU)
{
  int o = blockIdx.x*256 + threadIdx.x;   // < 64*256*160
  int bt = o/160, cp = o%160;
  float v0 = (cp < 150) ? x[(size_t)bt*D_ + 2*cp]   : 0.f;
  float v1 = (cp < 150) ? x[(size_t)bt*D_ + 2*cp+1] : 0.f;
  xpadU[o] = (u32)f2bf(v0) | ((u32)f2bf(v1) << 16);
}

// ---------------- K3: xproj[dir][b][t][g] (bf16) = xpad[b] @ Wim[dir][b]^T + bias ----------------
// Proven round-10 config: __launch_bounds__(256,2). (256,4) regressed (round 16).
__global__ void __launch_bounds__(256,2) k_gemm(
    const u16* __restrict__ xpad, const u16* __restrict__ Wim,
    const float* __restrict__ bias_m, u16* __restrict__ xproj)
{
  int bx = blockIdx.x;
  int b  = blockIdx.y, dir = blockIdx.z;
  int tt = bx >> 3, tg = bx & 7;
  int tid = threadIdx.x;
  int wid = tid >> 6, lane = tid & 63;
  int wr = wid >> 1, wc = wid & 1;
  __shared__ u16 As[128][72];
  __shared__ u16 Bs[128][72];
  const u16* Ap = xpad + ((size_t)b*T_ + tt*128)*DP_;
  const u16* Bp = Wim + (((size_t)dir*B_ + b)*G_ + tg*128)*DP_;
  f32x4 acc[4][4];
  #pragma unroll
  for (int i = 0; i < 4; ++i)
    #pragma unroll
    for (int j = 0; j < 4; ++j) acc[i][j] = (f32x4){0.f,0.f,0.f,0.f};
  for (int kt = 0; kt < 5; ++kt){
    int k0 = kt*64;
    #pragma unroll
    for (int i = 0; i < 4; ++i){
      int ci = i*256 + tid;
      int row = ci >> 3, cc = (ci & 7)*8;
      *(u32x4*)&As[row][cc] = *(const u32x4*)(Ap + (size_t)row*DP_ + k0 + cc);
      *(u32x4*)&Bs[row][cc] = *(const u32x4*)(Bp + (size_t)row*DP_ + k0 + cc);
    }
    __syncthreads();
    #pragma unroll
    for (int kk = 0; kk < 2; ++kk){
      short8 af[4], bfr[4];
      #pragma unroll
      for (int mi = 0; mi < 4; ++mi) af[mi]  = *(const short8*)&As[wr*64 + mi*16 + (lane&15)][kk*32 + (lane>>4)*8];
      #pragma unroll
      for (int ni = 0; ni < 4; ++ni) bfr[ni] = *(const short8*)&Bs[wc*64 + ni*16 + (lane&15)][kk*32 + (lane>>4)*8];
      #pragma unroll
      for (int mi = 0; mi < 4; ++mi)
        #pragma unroll
        for (int ni = 0; ni < 4; ++ni)
          acc[mi][ni] = __builtin_amdgcn_mfma_f32_16x16x32_bf16(af[mi], bfr[ni], acc[mi][ni], 0,0,0);
    }
    __syncthreads();
  }
  int r4 = (lane >> 4)*4, cg = lane & 15;
  const float* bmp = bias_m + (size_t)(dir*B_ + b)*G_;
  #pragma unroll
  for (int ni = 0; ni < 4; ++ni){
    int g = tg*128 + wc*64 + ni*16 + cg;
    float bsv = bmp[g];
    #pragma unroll
    for (int mi = 0; mi < 4; ++mi)
      #pragma unroll
      for (int j = 0; j < 4; ++j){
        int t = tt*128 + wr*64 + mi*16 + r4 + j;
        xproj[(((size_t)dir*B_ + b)*T_ + t)*G_ + g] = f2bf(acc[mi][ni][j] + bsv);
      }
  }
}

// ---------------- K4: recurrence, one chain (b,dir) per workgroup ----------------
// EXACT round-10 k_rec (436 us, best): 1024 threads, tid = gg*4 + q; 96 weight
// words in VGPR/AGPR + 32 in LDS; gates4 tail phase (wave-uniform tid<256);
// two __syncthreads; DPP qred; fast rcp/exp activations.
// Rounds 11-18 established this is the structural floor (~75% LDS-pipe-bound):
// residency >96 spills (r9/r13/r14), one-barrier fusion slower (r12), lgkmcnt
// barrier neutral (r15), gset-remap bank-conflicts (r18). Do not touch.
__global__ void __launch_bounds__(1024) k_rec(
    const u32* __restrict__ blob, const u32* __restrict__ xprojU,
    const int* __restrict__ length, float* __restrict__ out)
{
  int chain = blockIdx.x;
  int dir = chain >> 6, b = chain & 63;
  int tid = threadIdx.x;
  int gg = tid >> 2, q = tid & 3;
  __shared__ u32 wlds[8][1024][4];            // 128 KB: slot-quads 24..31
  __shared__ __align__(16) float gates4[256][4]; // 4 KB
  __shared__ __align__(16) u16 hp16[256];     // 512 B: h as f16
  const u32* hp32 = (const u32*)hp16;

  u32 w[96];
  const u32* bp = blob + (size_t)chain*32*1024*4;
  #pragma unroll
  for (int ii = 0; ii < 24; ++ii){
    u32x4 v = *(const u32x4*)(bp + ((size_t)ii*1024 + tid)*4);
    w[4*ii] = v.x; w[4*ii+1] = v.y; w[4*ii+2] = v.z; w[4*ii+3] = v.w;
  }
  #pragma unroll
  for (int ii = 24; ii < 32; ++ii){
    u32x4 v = *(const u32x4*)(bp + ((size_t)ii*1024 + tid)*4);
    *(u32x4*)&wlds[ii-24][tid][0] = v;
  }
  if (tid < 256) hp16[tid] = 0;
  int len = length[b];
  const u32* xp = xprojU + (size_t)chain*T_*512;
  float* outp = out + (size_t)b*T_*512 + dir*H_;
  float cst = 0.f;
  __syncthreads();

  for (int step = 0; step < len; ++step){
    int t = dir ? (len-1-step) : step;
    u32 xv0 = 0, xv1 = 0;
    if (q == 0){
      u32x2 xv = *(const u32x2*)(xp + (size_t)t*512 + 2*gg);
      xv0 = xv.x; xv1 = xv.y;
    }
    float a0 = 0.f, a1 = 0.f, a2 = 0.f, a3 = 0.f;
    #pragma unroll
    for (int cidx = 0; cidx < 8; ++cidx){
      int c4 = (cidx + 2*q) & 7;
      u32x4 hq = *(const u32x4*)&hp32[q*32 + c4*4];
      if (cidx < 6){
        #pragma unroll
        for (int e = 0; e < 4; ++e){
          u32 hv = hq[e];
          a0 = fdot2(w[cidx*16 + e*4 + 0], hv, a0);
          a1 = fdot2(w[cidx*16 + e*4 + 1], hv, a1);
          a2 = fdot2(w[cidx*16 + e*4 + 2], hv, a2);
          a3 = fdot2(w[cidx*16 + e*4 + 3], hv, a3);
        }
      } else {
        #pragma unroll
        for (int e = 0; e < 4; ++e){
          u32x4 wv = *(const u32x4*)&wlds[cidx*4 + e - 24][tid][0];
          u32 hv = hq[e];
          a0 = fdot2(wv.x, hv, a0);
          a1 = fdot2(wv.y, hv, a1);
          a2 = fdot2(wv.z, hv, a2);
          a3 = fdot2(wv.w, hv, a3);
        }
      }
    }
    // quad butterfly on VALU (DPP)
    a0 = qred(a0); a1 = qred(a1); a2 = qred(a2); a3 = qred(a3);
    if (q == 0){
      a0 += bflo(xv0); a1 += bfhi(xv0); a2 += bflo(xv1); a3 += bfhi(xv1);
      f32x4 g4; g4.x = a0; g4.y = a1; g4.z = a2; g4.w = a3;
      *(f32x4*)&gates4[gg][0] = g4;
    }
    __syncthreads();
    if (tid < 256){
      const float* gf = &gates4[0][0];   // gf[g] = gate g
      float ig = gf[tid],       fg = gf[256 + tid];
      float g_ = gf[512 + tid], og = gf[768 + tid];
      float i_ = sigm(ig), f_ = sigm(fg), gt = tanh_(g_), o_ = sigm(og);
      float cn = fmaf(f_, cst, i_*gt);
      float hy = o_ * tanh_(cn);
      cst = cn;
      ((u16*)hp16)[tid] = (u16)(pkf16(hy, hy) & 0xffffu);
      outp[(size_t)t*512 + tid] = hy;
    }
    __syncthreads();
  }
}

extern "C" void kernel_launch(void* const* d_in, const int* in_sizes, int n_in,
                              void* d_out, int out_size, void* d_ws, size_t ws_size,
                              hipStream_t stream)
{
  const float* x      = (const float*)d_in[0];
  const int*   length = (const int*)d_in[1];
  const int*   uidx   = (const int*)d_in[2];
  const int*   iidx   = (const int*)d_in[3];
  const float* uemb   = (const float*)d_in[4];
  const float* iemb   = (const float*)d_in[5];
  const float* W1     = (const float*)d_in[6];
  const float* b1     = (const float*)d_in[7];
  const float* W2     = (const float*)d_in[8];
  const float* Wih    = (const float*)d_in[9];
  const float* Whh    = (const float*)d_in[10];
  const float* bias   = (const float*)d_in[11];
  const float* Wih_r  = (const float*)d_in[12];
  const float* Whh_r  = (const float*)d_in[13];
  const float* bias_r = (const float*)d_in[14];
  float* out = (float*)d_out;
  char* ws = (char*)d_ws;

  float* coef   = (float*)(ws + 0);              //      2,048
  float* bias_m = (float*)(ws + 2048);           //    524,288
  u32*   blob   = (u32*)  (ws + 526336);         // 67,108,864 region (64 MB used)
  u16*   Wim    = (u16*)  (ws + 67635200);       // 83,886,080
  u16*   xpad   = (u16*)  (ws + 151521280);      // 10,485,760
  u16*   xproj  = (u16*)  (ws + 162007040);      // 67,108,864  -> total 229,115,904

  (void)hipMemsetAsync(d_out, 0, (size_t)out_size*sizeof(float), stream);
  if (ws_size < 229115904ull) return;  // fail loudly (all-zero output) if workspace too small

  hipLaunchKernelGGL(k_coef,    dim3(64),       dim3(64),   0, stream, uidx, iidx, uemb, iemb, W1, b1, W2, coef);
  hipLaunchKernelGGL(k_mix_whh, dim3(128,2,2),  dim3(256),  0, stream, Whh, Whh_r, bias, bias_r, coef, blob, bias_m);
  hipLaunchKernelGGL(k_mix_wi,  dim3(128,2,2),  dim3(256),  0, stream, Wih, Wih_r, coef, (u32*)Wim);
  hipLaunchKernelGGL(k_xpad,    dim3(10240),    dim3(256),  0, stream, x, (u32*)xpad);
  hipLaunchKernelGGL(k_gemm,    dim3(16,64,2),  dim3(256),  0, stream, xpad, Wim, bias_m, xproj);
  hipLaunchKernelGGL(k_rec,     dim3(128),      dim3(1024), 0, stream, blob, (const u32*)xproj, length, out);
}